// Round 7
// baseline (118.743 us; speedup 1.0000x reference)
//
#include <hip/hip_runtime.h>
#include <hip/hip_bf16.h>
#include <stdint.h>
#include <stddef.h>

#define TM 16      // output rows per tile
#define CIN 64     // C_in
#define NK3 27     // K3 neighbors
#define NK3P 28    // padded (kc=27 contributes zero)
#define COUT 128   // C_out
#define EPS_LN 1e-3f
#define KCH  (NK3 * CIN / 32)    // 54 real k-chunks of 32
#define KCHP (NK3P * CIN / 32)   // 56 padded k-chunks
#define NT   (COUT / 16)         // 8 column tiles
#define SPLIT 4                  // K-splits
#define KPB  (NK3P / SPLIT)      // 7 kc per split
#define PK_BYTES (NT * KCHP * 64 * 8 * 2)   // 458752

typedef __attribute__((ext_vector_type(8))) short   short8;   // MFMA A/B frag (8 bf16)
typedef __attribute__((ext_vector_type(4))) float   floatx4;  // MFMA C/D frag
typedef __attribute__((ext_vector_type(4))) unsigned short ushort4v;

__device__ __forceinline__ unsigned short f2b(float f) {
    union { float f; unsigned int i; } v;
    v.f = f;
    unsigned int i = v.i; // round-to-nearest-even bf16
    return (unsigned short)((i + 0x7fffu + ((i >> 16) & 1u)) >> 16);
}

// ---- kernel 1: pack W -> bf16 B-fragments (padded) + one-time dtype probe ----
__global__ __launch_bounds__(256) void pack_w(const float* __restrict__ Wm,
                                              const int* __restrict__ voxel_idx,
                                              const int* __restrict__ num_list,
                                              int Bc,
                                              unsigned short* __restrict__ pk,
                                              int* __restrict__ flags) {
    const int t = threadIdx.x;
    if (blockIdx.x == 0 && t < 64) {
        // int64 arrays (values < 2^31, nonneg) have all-zero odd 32-bit words
        int wv = voxel_idx[2 * t + 1];
        unsigned long long nz = __ballot(wv != 0);
        if (t == 0) {
            int f = (nz == 0ULL) ? 1 : 0;
            bool n64 = false;
            if (Bc >= 2) {
                n64 = (num_list[1] == 0) && (num_list[0] != 0);
                if (Bc >= 4) n64 = n64 && (num_list[3] == 0);
            }
            if (n64) f |= 2;
            flags[0] = f;
        }
    }
    int slot = blockIdx.x * 256 + t;             // 0 .. NT*KCHP*64-1
    int l  = slot & 63;
    int kk = (slot >> 6) % KCHP;
    int nt = slot / (64 * KCHP);
    short8 v = {0, 0, 0, 0, 0, 0, 0, 0};
    if (kk < KCH) {
        int q = l >> 4, n = l & 15;
        const float* src = Wm + (size_t)(kk * 32 + q * 8) * COUT + nt * 16 + n;
        #pragma unroll
        for (int j = 0; j < 8; ++j)
            v[j] = (short)f2b(src[(size_t)j * COUT]);
    }
    *(short8*)(pk + (size_t)slot * 8) = v;
}

// ---- kernel 2: split-K gather + MFMA partial GEMM ----
__global__ __launch_bounds__(256) void dpc_gemm_split(
    const float* __restrict__ features,   // fp32 [N][CIN]
    const int* __restrict__ voxel_idx,    // int32/int64 (flags) [M][NK3]
    const int* __restrict__ num_list,     // int32/int64 (flags) [B]
    const unsigned short* __restrict__ pk,
    const int* __restrict__ flags,
    float* __restrict__ partial,          // fp32 [SPLIT][Rtot][COUT]
    int N, int M, int B, int K, int Rtot)
{
    const int tile  = blockIdx.x / SPLIT;
    const int split = blockIdx.x - tile * SPLIT;
    const int R0 = tile * TM;
    const int t  = threadIdx.x;

    __shared__ int s_flags;
    __shared__ int s_src[TM];
    __shared__ int s_vid[TM][KPB];
    __shared__ __align__(16) unsigned short s_a[2][1024]; // [dbuf][chunk*512 + frag]

    if (t == 0) s_flags = flags[0];
    __syncthreads();
    const bool vidx64 = (s_flags & 1) != 0;
    const bool nl64   = (s_flags & 2) != 0;

    // per-row source index (validity handled in reduce kernel)
    if (t < TM) {
        int r = R0 + t;
        int src = 0;
        if (r < Rtot) {
            int b = r / K;
            int j = r - b * K;
            int offs = 0;
            for (int i = 0; i < B; ++i) {
                int v = nl64 ? num_list[2 * i] : num_list[i];
                if (i < b) offs += v;
            }
            src = offs + j;
            if (src < 0) src = 0;
            if (src > M - 1) src = M - 1;
        }
        s_src[t] = src;
    }
    __syncthreads();

    // stage this split's voxel ids (16 rows x KPB)
    for (int lin = t; lin < TM * KPB; lin += 256) {
        int i = lin / KPB;
        int k = lin - i * KPB;
        int kc = split * KPB + k;
        int v = -1;
        if (kc < NK3) {
            size_t e = (size_t)s_src[i] * NK3 + kc;
            v = vidx64 ? voxel_idx[2 * e] : voxel_idx[e];
        }
        s_vid[i][k] = v;
    }

    // staging geometry (A-fragment order; verified round 5)
    const int m  = t >> 4;
    const int c0 = (t & 15) * 4;
    const int chunk = c0 >> 5;
    const int q4    = (c0 & 31) >> 3;
    const int j0    = c0 & 7;
    const int aoff  = chunk * 512 + (q4 * 16 + m) * 8 + j0;

    auto gatherf4 = [&](int k) -> float4 {
        int idx = s_vid[m][k];
        float4 r = make_float4(0.f, 0.f, 0.f, 0.f);
        if (idx >= 0) {
            if (idx > N - 1) idx = N - 1;
            r = *(const float4*)(features + (size_t)idx * CIN + c0);
        }
        return r;
    };
    auto stash = [&](int buf, float4 v) {
        ushort4v u;
        u[0] = f2b(v.x); u[1] = f2b(v.y); u[2] = f2b(v.z); u[3] = f2b(v.w);
        *(ushort4v*)&s_a[buf][aoff] = u;
    };

    const int w    = t >> 6;
    const int lane = t & 63;
    const int nt0 = 2 * w, nt1 = 2 * w + 1;
    auto loadB = [&](int nt, int kk) -> short8 {
        return *(const short8*)(pk + ((size_t)(nt * KCHP + kk) * 64 + lane) * 8);
    };

    floatx4 acc0 = {0.f, 0.f, 0.f, 0.f};
    floatx4 acc1 = {0.f, 0.f, 0.f, 0.f};

    __syncthreads();            // s_vid ready
    stash(0, gatherf4(0));
    const int kkb = split * KPB * 2;
    short8 bb[4];
    bb[0] = loadB(nt0, kkb); bb[1] = loadB(nt1, kkb);
    bb[2] = loadB(nt0, kkb + 1); bb[3] = loadB(nt1, kkb + 1);
    __syncthreads();

    for (int i = 0; i < KPB; ++i) {
        const int  buf = i & 1;
        const bool hn  = (i + 1 < KPB);
        float4 pref;
        short8 nb[4];
        if (hn) {
            pref = gatherf4(i + 1);                     // LLC/HBM latency overlaps below
            const int kk = kkb + 2 * (i + 1);
            nb[0] = loadB(nt0, kk); nb[1] = loadB(nt1, kk);
            nb[2] = loadB(nt0, kk + 1); nb[3] = loadB(nt1, kk + 1);
        }
        const short8 a0 = *(const short8*)&s_a[buf][      lane * 8];
        const short8 a1 = *(const short8*)&s_a[buf][512 + lane * 8];

        acc0 = __builtin_amdgcn_mfma_f32_16x16x32_bf16(a0, bb[0], acc0, 0, 0, 0);
        acc1 = __builtin_amdgcn_mfma_f32_16x16x32_bf16(a0, bb[1], acc1, 0, 0, 0);
        acc0 = __builtin_amdgcn_mfma_f32_16x16x32_bf16(a1, bb[2], acc0, 0, 0, 0);
        acc1 = __builtin_amdgcn_mfma_f32_16x16x32_bf16(a1, bb[3], acc1, 0, 0, 0);

        if (hn) stash(buf ^ 1, pref);
        __syncthreads();
        if (hn) { bb[0] = nb[0]; bb[1] = nb[1]; bb[2] = nb[2]; bb[3] = nb[3]; }
    }

    // partial C store (C/D layout: col=lane&15, row=(lane>>4)*4+reg)
    {
        const int q = lane >> 4, n = lane & 15;
        float* base = partial + (size_t)split * Rtot * COUT + (size_t)R0 * COUT;
        #pragma unroll
        for (int reg = 0; reg < 4; ++reg) {
            int row = q * 4 + reg;
            base[(size_t)row * COUT + nt0 * 16 + n] = acc0[reg];
            base[(size_t)row * COUT + nt1 * 16 + n] = acc1[reg];
        }
    }
}

// ---- kernel 3: reduce partials + LayerNorm + ReLU + coords/resample ----
__global__ __launch_bounds__(256) void dpc_reduce_ln(
    const float* __restrict__ partial,    // [SPLIT][Rtot][COUT]
    const float* __restrict__ center,
    const int* __restrict__ num_list,
    const int* __restrict__ flags,
    const float* __restrict__ gamma_,
    const float* __restrict__ beta_,
    float* __restrict__ out_feat,
    float* __restrict__ out_coor,
    int M, int B, int K, int Rtot)
{
    const int t  = threadIdx.x;
    const int R0 = blockIdx.x * TM;

    __shared__ int s_flags;
    __shared__ int s_src[TM];
    __shared__ int s_valid[TM];

    if (t == 0) s_flags = flags[0];
    __syncthreads();
    const bool nl64 = (s_flags & 2) != 0;

    if (t < TM) {
        int r = R0 + t;
        int src = 0, valid = 0;
        if (r < Rtot) {
            int b = r / K;
            int j = r - b * K;
            int offs = 0, nlb = 0;
            for (int i = 0; i < B; ++i) {
                int v = nl64 ? num_list[2 * i] : num_list[i];
                if (i < b) offs += v;
                if (i == b) nlb = v;
            }
            int end = nlb < K ? nlb : K;
            valid = (j < end) ? 1 : 0;
            src = offs + j;
            if (src < 0) src = 0;
            if (src > M - 1) src = M - 1;
        }
        s_src[t] = src;
        s_valid[t] = valid;
    }
    __syncthreads();

    if (t < TM * 4) {
        int i = t >> 2, comp = t & 3;
        int r = R0 + i;
        if (r < Rtot) {
            float val;
            if (comp == 0) {
                int b = r / K;
                val = (b < B - 1) ? (float)(b + 1) : 0.0f;
            } else {
                val = s_valid[i] ? center[(size_t)s_src[i] * 3 + comp - 1] : 0.0f;
            }
            out_coor[(size_t)r * 4 + comp] = val;
        }
    }

    const int h  = t >> 6;
    const int c2 = (t & 63) * 2;
    const float g0  = gamma_[c2];
    const float g1  = gamma_[c2 + 1];
    const float be0 = beta_[c2];
    const float be1 = beta_[c2 + 1];

    #pragma unroll
    for (int i = 0; i < 4; ++i) {
        int row = h * 4 + i;
        int r = R0 + row;
        float a0 = 0.f, a1 = 0.f;
        #pragma unroll
        for (int s = 0; s < SPLIT; ++s) {
            const float2 v = *(const float2*)(partial + ((size_t)s * Rtot + r) * COUT + c2);
            a0 += v.x; a1 += v.y;
        }
        float s  = a0 + a1;
        float ss = a0 * a0 + a1 * a1;
        #pragma unroll
        for (int mm = 1; mm < 64; mm <<= 1) {   // 64-lane butterfly
            s  += __shfl_xor(s,  mm, 64);
            ss += __shfl_xor(ss, mm, 64);
        }
        float mu   = s * (1.0f / COUT);
        float var  = ss * (1.0f / COUT) - mu * mu;
        float rstd = rsqrtf(var + EPS_LN);
        float v0 = (a0 - mu) * rstd * g0 + be0;
        float v1 = (a1 - mu) * rstd * g1 + be1;
        v0 = fmaxf(v0, 0.f);
        v1 = fmaxf(v1, 0.f);
        if (!s_valid[row]) { v0 = 0.f; v1 = 0.f; }
        out_feat[(size_t)r * COUT + c2]     = v0;
        out_feat[(size_t)r * COUT + c2 + 1] = v1;
    }
}

extern "C" void kernel_launch(void* const* d_in, const int* in_sizes, int n_in,
                              void* d_out, int out_size, void* d_ws, size_t ws_size,
                              hipStream_t stream) {
    const float* features = (const float*)d_in[0];
    const float* center   = (const float*)d_in[1];
    const int*   vidx     = (const int*)d_in[2];
    const int*   num_list = (const int*)d_in[3];
    const float* Wm       = (const float*)d_in[4];
    const float* gamma_   = (const float*)d_in[5];
    const float* beta_    = (const float*)d_in[6];

    const int B    = in_sizes[3];                 // 4
    const int Cout = in_sizes[5];                 // 128
    const int M    = in_sizes[1] / 3;             // 40000
    const int K3v  = in_sizes[2] / M;             // 27
    const int Cin  = (in_sizes[4] / Cout) / K3v;  // 64
    const int N    = in_sizes[0] / Cin;           // 200000
    const int Rtot = out_size / (Cout + 4);       // 8192
    const int K    = Rtot / B;                    // 2048

    float* out_feat = (float*)d_out;
    float* out_coor = out_feat + (size_t)Rtot * Cout;

    unsigned short* pk   = (unsigned short*)d_ws;
    int*   flags   = (int*)((char*)d_ws + PK_BYTES);
    float* partial = (float*)((char*)d_ws + PK_BYTES + 16);

    const int pack_grid = (NT * KCHP * 64) / 256;       // 112
    pack_w<<<dim3(pack_grid), dim3(256), 0, stream>>>(Wm, vidx, num_list, B, pk, flags);

    const int tiles = (Rtot + TM - 1) / TM;             // 512
    dpc_gemm_split<<<dim3(tiles * SPLIT), dim3(256), 0, stream>>>(
        features, vidx, num_list, pk, flags, partial, N, M, B, K, Rtot);

    dpc_reduce_ln<<<dim3(tiles), dim3(256), 0, stream>>>(
        partial, center, num_list, flags, gamma_, beta_,
        out_feat, out_coor, M, B, K, Rtot);
}